// Round 2
// baseline (434.409 us; speedup 1.0000x reference)
//
#include <hip/hip_runtime.h>
#include <math.h>

// Fused PatchTST-MoE forecaster for MI355X.
// R2 design: ws-minimal (3.5 MB) + runtime fp32/bf16 input detection.
// One block per (b,v): normalize -> patch-embed(+PE) -> fp32 gating/top2 ->
// dense 8-expert FFN (MFMA 16x16x32 bf16) -> head matvec -> de-norm -> out.

#define NTOK 16384
typedef __attribute__((ext_vector_type(8))) short bf16x8;
typedef __attribute__((ext_vector_type(4))) float f32x4;

__device__ __forceinline__ float bf2f(unsigned short u){
  unsigned x = ((unsigned)u) << 16; float f; __builtin_memcpy(&f, &x, 4); return f;
}
__device__ __forceinline__ unsigned short f2bf(float f){
  unsigned x; __builtin_memcpy(&x, &f, 4);
  return (unsigned short)((x + 0x7FFFu + ((x >> 16) & 1u)) >> 16);
}
__device__ __forceinline__ float ldin(const void* p, int i, int f32){
  return f32 ? ((const float*)p)[i] : bf2f(((const unsigned short*)p)[i]);
}
__device__ __forceinline__ void stout(void* p, int i, float v, int f32){
  if (f32) ((float*)p)[i] = v; else ((unsigned short*)p)[i] = f2bf(v);
}
__device__ __forceinline__ f32x4 mfma16(bf16x8 a, bf16x8 b, f32x4 c){
  return __builtin_amdgcn_mfma_f32_16x16x32_bf16(a, b, c, 0, 0, 0);
}

// ---- ws layout (total 3706112 B ~ 3.5 MB) ----
#define OFF_FLAG   0
#define OFF_SUMS   64        // 17 floats
#define OFF_MEANS  256       // 256 f
#define OFF_STDS   1280      // 256 f
#define OFF_RSTDS  2304      // 256 f
#define OFF_PE     3328      // 64*128 f32 = 32768 B
#define OFF_W1T    36096     // 8*512*128 bf16 = 1048576 B
#define OFF_W2T    1084672   // 8*128*512 bf16 = 1048576 B
#define OFF_WHT    2133248   // 96*8192 bf16 = 1572864 B

// ========== K0: dtype detect + zero sums ==========
__global__ __launch_bounds__(256) void k_detect(const unsigned short* __restrict__ xe,
                                                int* flag, float* sums){
  __shared__ int cnt;
  int t = threadIdx.x;
  if (t == 0) cnt = 0;
  __syncthreads();
  int c = 0;
  for (int i = t; i < 131072; i += 256){
    unsigned short u = xe[i];
    int ex = (u >> 7) & 0xFF;
    if (ex == 0xFF || (ex == 0 && (u & 0x7F))) c++;
  }
  atomicAdd(&cnt, c);
  __syncthreads();
  if (t == 0) flag[0] = (cnt >= 4) ? 1 : 0;   // genuine bf16 data: cnt == 0
  if (t < 17) sums[t] = 0.f;
}

// ========== K1: per-(b,v) stats (blocks 0..7) + PE table (block 8) ==========
__global__ __launch_bounds__(256) void k_prep(const void* __restrict__ xe, const int* flg,
                                              float* means, float* stds, float* rstds,
                                              float* pe){
  int t = threadIdx.x;
  int f32 = flg[0];
  if (blockIdx.x == 8){
    for (int i = t; i < 8192; i += 256){
      int p = i >> 7, d = i & 127;
      float freq = expf(-(float)(d & ~1) * 0.07195578415606394f);  // ln(1e4)/128
      float ang = (float)p * freq;
      pe[i] = (d & 1) ? cosf(ang) : sinf(ang);
    }
    return;
  }
  int b = blockIdx.x;
  int v = t & 31, g = t >> 5;
  float s = 0.f, ss = 0.f;
  for (int k = 0; k < 64; ++k){
    int l = g*64 + k;
    float x = ldin(xe, (b*512 + l)*32 + v, f32);
    s += x; ss += x*x;
  }
  __shared__ float sh_s[8][32], sh_ss[8][32];
  sh_s[g][v] = s; sh_ss[g][v] = ss;
  __syncthreads();
  if (t < 32){
    float S = 0.f, SS = 0.f;
    for (int gg = 0; gg < 8; ++gg){ S += sh_s[gg][t]; SS += sh_ss[gg][t]; }
    float m = S / 512.f;
    float sd = sqrtf(SS / 512.f - m*m + 1e-5f);
    int bv = b*32 + t;
    means[bv] = m; stds[bv] = sd; rstds[bv] = 1.f/sd;
  }
}

// ========== K2: weight transposes (to bf16 ws) ==========
// W1T[e][h][d]=W1[e][d][h]; W2T[e][d][h]=W2[e][h][d]; WhT[n][k]=Wh[k][n]
__global__ __launch_bounds__(256) void k_tr(const void* __restrict__ W1,
                                            const void* __restrict__ W2,
                                            const void* __restrict__ Wh, const int* flg,
                                            unsigned short* W1T, unsigned short* W2T,
                                            unsigned short* WhT){
  int f32 = flg[0];
  int idx = blockIdx.x*256 + threadIdx.x;
  if (blockIdx.x < 2048){
    int o = idx;
    int e = o >> 16, r = (o >> 7) & 511, d = o & 127;
    W1T[o] = f2bf(ldin(W1, e*65536 + d*512 + r, f32));
  } else if (blockIdx.x < 4096){
    int o = idx - 524288;
    int e = o >> 16, d = (o >> 9) & 127, hh = o & 511;
    W2T[o] = f2bf(ldin(W2, e*65536 + hh*128 + d, f32));
  } else {
    int o = idx - 1048576;
    int n = o >> 13, k = o & 8191;
    WhT[o] = f2bf(ldin(Wh, k*96 + n, f32));
  }
}

// ========== K3: fully fused per-(b,v) pipeline ==========
__global__ __launch_bounds__(256, 2) void k_moe(const void* __restrict__ xe,
                                                const void* __restrict__ Wp,
                                                const void* __restrict__ Wg,
                                                const void* __restrict__ b1g,
                                                const void* __restrict__ b2g,
                                                const void* __restrict__ bh,
                                                const unsigned short* __restrict__ W1T,
                                                const unsigned short* __restrict__ W2T,
                                                const unsigned short* __restrict__ WhT,
                                                const int* flg,
                                                const float* __restrict__ means,
                                                const float* __restrict__ stds,
                                                const float* __restrict__ rstds,
                                                const float* __restrict__ peg,
                                                float* sums, void* __restrict__ out){
  __shared__ __align__(16) char lds[64512];
  // phase-B layout (bytes): Xs@0[64][136]bf16, Bu1@17408[64][136], Bu2@34816[128][72],
  //                         Ag@53248[64][72], cws@62464[64][8]f32
  short* Xs  = (short*)(lds);
  short* Bu1 = (short*)(lds + 17408);
  short* Bu2 = (short*)(lds + 34816);
  short* Ag  = (short*)(lds + 53248);
  float (*cws)[8] = (float(*)[8])(lds + 62464);
  // phase-A overlays
  float* WpL = (float*)(lds);            // [16][128] (over Xs)
  float* Xf  = (float*)(lds + 17408);    // [64][128] (over Bu1/Bu2)
  float* xn  = (float*)(lds + 53248);    // [512]     (over Ag)
  float* lp  = (float*)(lds + 55296);    // [64][2][8]
  float* taux= (float*)(lds + 59520);    // [64][9]
  // phase-C/D overlays
  float* ytr = (float*)(lds + 17408);    // [128][68] f32 (over Bu1/Bu2)
  float* dpart=(float*)(lds + 53248);    // [96][2]

  int bv = blockIdx.x;
  int b = bv >> 5, v = bv & 31;
  int t = threadIdx.x;
  int f32 = flg[0];
  int wave = t >> 6, lane = t & 63;
  int quad = lane >> 4, li = lane & 15;
  int r0 = (wave & 1) * 32;
  int c1 = (wave >> 1) * 32;
  int c2 = (wave >> 1) * 64;

  // ---- Phase A: normalize + patch-embed + PE + gating ----
  float mean = means[bv], rstd = rstds[bv];
  #pragma unroll
  for (int it = 0; it < 2; ++it){
    int i = it*256 + t;
    xn[i] = (ldin(xe, (b*512 + i)*32 + v, f32) - mean) * rstd;
  }
  #pragma unroll
  for (int it = 0; it < 8; ++it){
    int i = it*256 + t;
    WpL[i] = ldin(Wp, i, f32);
  }
  __syncthreads();
  {
    int p = t >> 2, q = t & 3;
    int base = p*8;
    float tv[16];
    #pragma unroll
    for (int l = 0; l < 16; ++l){
      int xi = base + l; if (xi > 511) xi = 511;   // edge pad
      tv[l] = xn[xi];
    }
    for (int dd = 0; dd < 32; ++dd){
      int d = q*32 + dd;
      float acc = peg[p*128 + d];
      #pragma unroll
      for (int l = 0; l < 16; ++l) acc += tv[l] * WpL[l*128 + d];
      Xf[p*128 + d] = acc;
    }
  }
  __syncthreads();
  if (t < 128){
    int p = t >> 1, half = t & 1;
    float s[8] = {0,0,0,0,0,0,0,0};
    for (int d = half*64; d < half*64 + 64; ++d){
      float xv = Xf[p*128 + d];
      #pragma unroll
      for (int e = 0; e < 8; ++e) s[e] += xv * ldin(Wg, d*8 + e, f32);
    }
    #pragma unroll
    for (int e = 0; e < 8; ++e) lp[(p*2 + half)*8 + e] = s[e];
  }
  __syncthreads();
  if (t < 64){
    int p = t;
    float lg[8];
    #pragma unroll
    for (int e = 0; e < 8; ++e) lg[e] = lp[(p*2)*8 + e] + lp[(p*2+1)*8 + e];
    float m = lg[0];
    #pragma unroll
    for (int e = 1; e < 8; ++e) m = fmaxf(m, lg[e]);
    float pr[8]; float se = 0.f;
    #pragma unroll
    for (int e = 0; e < 8; ++e){ pr[e] = expf(lg[e] - m); se += pr[e]; }
    float inv = 1.f / se;
    float lse = m + logf(se);
    #pragma unroll
    for (int e = 0; e < 8; ++e) pr[e] *= inv;
    float best = -1.f; int bi = 0;
    #pragma unroll
    for (int e = 0; e < 8; ++e) if (pr[e] > best){ best = pr[e]; bi = e; }
    float sec = -1.f; int si = 0;
    #pragma unroll
    for (int e = 0; e < 8; ++e) if (e != bi && pr[e] > sec){ sec = pr[e]; si = e; }
    #pragma unroll
    for (int e = 0; e < 8; ++e){
      cws[p][e] = (e == bi) ? best : ((e == si) ? sec : 0.f);
      taux[p*9 + e] = pr[e];
    }
    taux[p*9 + 8] = lse * lse;
  }
  __syncthreads();
  if (t < 17){
    float s = 0.f;
    if (t < 8){ for (int p = 0; p < 64; ++p) s += taux[p*9 + t]; }
    else if (t < 16){ int e = t - 8; for (int p = 0; p < 64; ++p) s += (cws[p][e] != 0.f) ? 1.f : 0.f; }
    else { for (int p = 0; p < 64; ++p) s += taux[p*9 + 8]; }
    atomicAdd(sums + t, s);
  }
  #pragma unroll
  for (int it = 0; it < 32; ++it){     // Xf (fp32) -> Xs (bf16) for MFMA
    int idx = it*256 + t;
    int row = idx >> 7, c = idx & 127;
    Xs[row*136 + c] = (short)f2bf(Xf[row*128 + c]);
  }

  // ---- Phase B: dense 8-expert FFN, MFMA ----
  f32x4 Yacc[2][4];
  #pragma unroll
  for (int a = 0; a < 2; ++a)
    #pragma unroll
    for (int bb2 = 0; bb2 < 4; ++bb2){ f32x4 z = {0.f,0.f,0.f,0.f}; Yacc[a][bb2] = z; }

  for (int e = 0; e < 8; ++e){
    for (int hc = 0; hc < 8; ++hc){
      __syncthreads();   // prior-iter consumers done (first iter: phase-A writes done)
      #pragma unroll
      for (int pass = 0; pass < 4; ++pass){
        int idx = pass*256 + t;
        int row = idx >> 4, kg = idx & 15;
        *(bf16x8*)(Bu1 + row*136 + kg*8) =
          *(const bf16x8*)(W1T + e*65536 + (hc*64 + row)*128 + kg*8);
      }
      #pragma unroll
      for (int pass = 0; pass < 4; ++pass){
        int idx = pass*256 + t;
        int row = idx >> 3, kg = idx & 7;
        *(bf16x8*)(Bu2 + row*72 + kg*8) =
          *(const bf16x8*)(W2T + e*65536 + row*512 + hc*64 + kg*8);
      }
      __syncthreads();
      // GEMM1: (64 tok x 64 h), K=128
      f32x4 acc1[2][2];
      #pragma unroll
      for (int a = 0; a < 2; ++a)
        #pragma unroll
        for (int bb2 = 0; bb2 < 2; ++bb2){ f32x4 z = {0.f,0.f,0.f,0.f}; acc1[a][bb2] = z; }
      #pragma unroll
      for (int ks = 0; ks < 4; ++ks){
        int kk = ks*32 + quad*8;
        bf16x8 a0 = *(const bf16x8*)(Xs + (r0 + li)*136 + kk);
        bf16x8 a1 = *(const bf16x8*)(Xs + (r0 + 16 + li)*136 + kk);
        bf16x8 b0 = *(const bf16x8*)(Bu1 + (c1 + li)*136 + kk);
        bf16x8 b1f = *(const bf16x8*)(Bu1 + (c1 + 16 + li)*136 + kk);
        acc1[0][0] = mfma16(a0, b0,  acc1[0][0]);
        acc1[0][1] = mfma16(a0, b1f, acc1[0][1]);
        acc1[1][0] = mfma16(a1, b0,  acc1[1][0]);
        acc1[1][1] = mfma16(a1, b1f, acc1[1][1]);
      }
      float bias0 = ldin(b1g, e*512 + hc*64 + c1 + li, f32);
      float bias1 = ldin(b1g, e*512 + hc*64 + c1 + 16 + li, f32);
      #pragma unroll
      for (int rt = 0; rt < 2; ++rt){
        #pragma unroll
        for (int ct = 0; ct < 2; ++ct){
          float bias = ct ? bias1 : bias0;
          int colL = c1 + ct*16 + li;
          #pragma unroll
          for (int r = 0; r < 4; ++r){
            int row = r0 + rt*16 + quad*4 + r;
            float val = acc1[rt][ct][r] + bias;
            float g = 0.5f * val * (1.f + erff(val * 0.70710678118654752f));
            Ag[row*72 + colL] = (short)f2bf(g * cws[row][e]);
          }
        }
      }
      __syncthreads();
      // GEMM2: (64 tok x 128 d), K=64
      #pragma unroll
      for (int ks = 0; ks < 2; ++ks){
        int kk = ks*32 + quad*8;
        bf16x8 a0 = *(const bf16x8*)(Ag + (r0 + li)*72 + kk);
        bf16x8 a1 = *(const bf16x8*)(Ag + (r0 + 16 + li)*72 + kk);
        bf16x8 bbv[4];
        #pragma unroll
        for (int ct = 0; ct < 4; ++ct)
          bbv[ct] = *(const bf16x8*)(Bu2 + (c2 + ct*16 + li)*72 + kk);
        #pragma unroll
        for (int ct = 0; ct < 4; ++ct){
          Yacc[0][ct] = mfma16(a0, bbv[ct], Yacc[0][ct]);
          Yacc[1][ct] = mfma16(a1, bbv[ct], Yacc[1][ct]);
        }
      }
    }
  }

  // ---- Phase C: +b2 epilogue, transpose to ytr[d][p] (fp32) ----
  __syncthreads();
  #pragma unroll
  for (int ct = 0; ct < 4; ++ct){
    int col = c2 + ct*16 + li;   // d
    float b2v[8];
    #pragma unroll
    for (int e = 0; e < 8; ++e) b2v[e] = ldin(b2g, e*128 + col, f32);
    #pragma unroll
    for (int rt = 0; rt < 2; ++rt){
      #pragma unroll
      for (int r = 0; r < 4; ++r){
        int row = r0 + rt*16 + quad*4 + r;   // p
        float add = 0.f;
        #pragma unroll
        for (int e = 0; e < 8; ++e) add += cws[row][e] * b2v[e];
        ytr[col*68 + row] = Yacc[rt][ct][r] + add;
      }
    }
  }
  __syncthreads();

  // ---- Phase D: head matvec dec[n] = flat . WhT[n] + de-norm + store ----
  if (t < 192){
    int n = t >> 1, half = t & 1;
    float s = 0.f;
    const unsigned short* wrow = WhT + n*8192 + half*4096;
    const float* yb = ytr + half*64*68;
    for (int d = 0; d < 64; ++d){
      const float* yr = yb + d*68;
      #pragma unroll
      for (int pp = 0; pp < 8; ++pp){
        bf16x8 wv = *(const bf16x8*)(wrow + d*64 + pp*8);
        float4 y0 = *(const float4*)(yr + pp*8);
        float4 y1 = *(const float4*)(yr + pp*8 + 4);
        s += bf2f((unsigned short)wv[0])*y0.x + bf2f((unsigned short)wv[1])*y0.y
           + bf2f((unsigned short)wv[2])*y0.z + bf2f((unsigned short)wv[3])*y0.w
           + bf2f((unsigned short)wv[4])*y1.x + bf2f((unsigned short)wv[5])*y1.y
           + bf2f((unsigned short)wv[6])*y1.z + bf2f((unsigned short)wv[7])*y1.w;
      }
    }
    dpart[n*2 + half] = s;
  }
  __syncthreads();
  if (t < 96){
    float dec = dpart[t*2] + dpart[t*2 + 1] + ldin(bh, t, f32);
    float val = dec * stds[bv] + mean;
    stout(out, b*3072 + t*32 + v, val, f32);
  }
}

// ========== K4: aux scalar ==========
__global__ __launch_bounds__(64) void k_aux(const float* __restrict__ sums, const int* flg,
                                            void* out){
  if (threadIdx.x == 0){
    float bal = 0.f;
    for (int e = 0; e < 8; ++e) bal += (sums[e] / 16384.f) * (sums[8+e] / 16384.f);
    bal = 8.f * bal / 2.f;
    float aux = 0.01f * bal + 0.001f * (sums[16] / 16384.f);
    stout(out, 24576, aux, flg[0]);
  }
}

extern "C" void kernel_launch(void* const* d_in, const int* in_sizes, int n_in,
                              void* d_out, int out_size, void* d_ws, size_t ws_size,
                              hipStream_t stream){
  const void* xe = d_in[0];
  const void* Wp = d_in[4];
  const void* Wg = d_in[5];
  const void* W1 = d_in[6];
  const void* b1 = d_in[7];
  const void* W2 = d_in[8];
  const void* b2 = d_in[9];
  const void* Wh = d_in[10];
  const void* bh = d_in[11];

  char* ws = (char*)d_ws;
  int*   flag  = (int*)(ws + OFF_FLAG);
  float* sums  = (float*)(ws + OFF_SUMS);
  float* means = (float*)(ws + OFF_MEANS);
  float* stds  = (float*)(ws + OFF_STDS);
  float* rstds = (float*)(ws + OFF_RSTDS);
  float* pe    = (float*)(ws + OFF_PE);
  unsigned short* W1T = (unsigned short*)(ws + OFF_W1T);
  unsigned short* W2T = (unsigned short*)(ws + OFF_W2T);
  unsigned short* WhT = (unsigned short*)(ws + OFF_WHT);

  k_detect<<<1, 256, 0, stream>>>((const unsigned short*)xe, flag, sums);
  k_prep<<<9, 256, 0, stream>>>(xe, flag, means, stds, rstds, pe);
  k_tr<<<7168, 256, 0, stream>>>(W1, W2, Wh, flag, W1T, W2T, WhT);
  k_moe<<<256, 256, 0, stream>>>(xe, Wp, Wg, b1, b2, bh, W1T, W2T, WhT, flag,
                                 means, stds, rstds, pe, sums, d_out);
  k_aux<<<1, 64, 0, stream>>>(sums, flag, d_out);
}

// Round 3
// 242.414 us; speedup vs baseline: 1.7920x; 1.7920x over previous
//
#include <hip/hip_runtime.h>
#include <math.h>

// R3: occupancy-first restructure.
// memset ->  k_detect(64) -> k_prep_tr(1793: PE + tiled W transposes)
// -> k_embed(256: stats+patch-embed+gate+aux) -> k_moe(2048: per-(bv,e) FFN, atomic Y)
// -> k_flat(256: Y+cw*b2 -> flat bf16) -> k_head(256: MFMA head, K-split, atomic dec)
// -> k_final(96: de-norm + aux)

typedef __attribute__((ext_vector_type(8))) short bf16x8;
typedef __attribute__((ext_vector_type(4))) float f32x4;

__device__ __forceinline__ float bf2f(unsigned short u){
  unsigned x = ((unsigned)u) << 16; float f; __builtin_memcpy(&f, &x, 4); return f;
}
__device__ __forceinline__ unsigned short f2bf(float f){
  unsigned x; __builtin_memcpy(&x, &f, 4);
  return (unsigned short)((x + 0x7FFFu + ((x >> 16) & 1u)) >> 16);
}
__device__ __forceinline__ float ldin(const void* p, int i, int f32){
  return f32 ? ((const float*)p)[i] : bf2f(((const unsigned short*)p)[i]);
}
__device__ __forceinline__ void stout(void* p, int i, float v, int f32){
  if (f32) ((float*)p)[i] = v; else ((unsigned short*)p)[i] = f2bf(v);
}
__device__ __forceinline__ f32x4 mfma16(bf16x8 a, bf16x8 b, f32x4 c){
  return __builtin_amdgcn_mfma_f32_16x16x32_bf16(a, b, c, 0, 0, 0);
}
// tanh-form gelu: x * sigmoid(1.5957691216*(x + 0.044715 x^3)); |dev vs erf-gelu| <~3e-4
__device__ __forceinline__ float gelu_fast(float v){
  float u = v*v;
  float inner = v * fmaf(0.044715f, u, 1.0f);
  float e = __expf(-1.5957691216f * inner);
  return v / (1.0f + e);     // v * sigmoid; e=inf -> 0, e=0 -> v  (no NaN)
}

// ---- ws layout (total ~20.1 MB) ----
#define OFF_CNT    0
#define OFF_SUMS   64
#define OFF_MEANS  256
#define OFF_STDS   1280
#define OFF_RSTDS  2304
#define OFF_PE     3328        // 8192 f32
#define OFF_DEC    36096       // 24576 f32 (memset 0)
#define OFF_W1T    134400      // 8*512*128 bf16
#define OFF_W2T    1182976     // 8*128*512 bf16
#define OFF_WHT    2231552     // 96*8192 bf16
#define OFF_CW     3804416     // 16384*8 f32
#define OFF_XFBF   4328704     // 16384*128 bf16
#define OFF_FLATB  8523008     // 256*8192 bf16
#define OFF_YG     12717312    // 16384*128 f32 (memset 0)

// ========== K0: dtype detect (count fp32-bit-pattern evidence) ==========
__global__ __launch_bounds__(256) void k_detect(const unsigned short* __restrict__ xe,
                                                int* cnt){
  __shared__ int sc;
  int t = threadIdx.x;
  if (t == 0) sc = 0;
  __syncthreads();
  int c = 0;
  int base = blockIdx.x * 2048;
  for (int k = 0; k < 8; ++k){
    unsigned short u = xe[base + k*256 + t];
    int ex = (u >> 7) & 0xFF;
    if (ex == 0xFF || (ex == 0 && (u & 0x7F))) c++;
  }
  atomicAdd(&sc, c);
  __syncthreads();
  if (t == 0 && sc) atomicAdd(cnt, sc);
}

// ========== K1: PE table (block 0) + tiled weight transposes ==========
__global__ __launch_bounds__(256) void k_prep_tr(const void* __restrict__ W1,
                                                 const void* __restrict__ W2,
                                                 const void* __restrict__ Wh,
                                                 const int* cnt, float* pe,
                                                 unsigned short* W1T, unsigned short* W2T,
                                                 unsigned short* WhT){
  int t = threadIdx.x;
  if (blockIdx.x == 0){
    for (int i = t; i < 8192; i += 256){
      int p = i >> 7, d = i & 127;
      float freq = __expf(-(float)(d & ~1) * 0.07195578415606394f);
      float ang = (float)p * freq;
      pe[i] = (d & 1) ? __cosf(ang) : __sinf(ang);
    }
    return;
  }
  int f32 = (cnt[0] >= 4);
  __shared__ float tile[32*33];
  int tb = blockIdx.x - 1;
  int r = t >> 3, cg = (t & 7) * 4;
  const void* src; unsigned short* dst;
  int in0, instride, out0, outstride;
  if (tb < 512){            // W1 [e][d 128][h 512] -> W1T [e][h][d]
    int e = tb >> 6, ti = tb & 63, d0 = (ti & 3) * 32, h0 = (ti >> 2) * 32;
    src = W1; dst = W1T;
    in0 = e*65536 + d0*512 + h0; instride = 512;
    out0 = e*65536 + h0*128 + d0; outstride = 128;
  } else if (tb < 1024){    // W2 [e][h 512][d 128] -> W2T [e][d][h]
    int tc = tb - 512;
    int e = tc >> 6, ti = tc & 63, d0 = (ti & 3) * 32, h0 = (ti >> 2) * 32;
    src = W2; dst = W2T;
    in0 = e*65536 + h0*128 + d0; instride = 128;
    out0 = e*65536 + d0*512 + h0; outstride = 512;
  } else {                  // Wh [k 8192][n 96] -> WhT [n][k]
    int tc = tb - 1024;
    int kt = tc / 3, nt = tc - kt*3;
    int k0 = kt*32, n0 = nt*32;
    src = Wh; dst = WhT;
    in0 = k0*96 + n0; instride = 96;
    out0 = n0*8192 + k0; outstride = 8192;
  }
  #pragma unroll
  for (int j = 0; j < 4; ++j)
    tile[r*33 + cg + j] = ldin(src, in0 + r*instride + cg + j, f32);
  __syncthreads();
  ushort4 o;
  o.x = f2bf(tile[(cg+0)*33 + r]);
  o.y = f2bf(tile[(cg+1)*33 + r]);
  o.z = f2bf(tile[(cg+2)*33 + r]);
  o.w = f2bf(tile[(cg+3)*33 + r]);
  *(ushort4*)(dst + out0 + r*outstride + cg) = o;
}

// ========== K2: per-bv stats + patch embed + PE + gating + aux ==========
__global__ __launch_bounds__(256) void k_embed(const void* __restrict__ xe,
                                               const void* __restrict__ Wp,
                                               const void* __restrict__ Wg,
                                               const int* cnt,
                                               const float* __restrict__ peg,
                                               float* means, float* stds, float* rstds,
                                               unsigned short* xfbf, float* cwg,
                                               float* sums){
  __shared__ float xn[512];
  __shared__ float WpL[2048];
  __shared__ float Xf[8192];
  __shared__ float lp[1024];
  __shared__ float taux[576];
  __shared__ float reds[256], redss[256];
  __shared__ float msh[2];

  int bv = blockIdx.x;
  int b = bv >> 5, v = bv & 31;
  int t = threadIdx.x;
  int f32 = (cnt[0] >= 4);

  float x0 = ldin(xe, (b*512 + t)*32 + v, f32);
  float x1 = ldin(xe, (b*512 + t + 256)*32 + v, f32);
  xn[t] = x0; xn[t+256] = x1;
  reds[t] = x0 + x1; redss[t] = x0*x0 + x1*x1;
  #pragma unroll
  for (int it = 0; it < 8; ++it)
    WpL[it*256 + t] = ldin(Wp, it*256 + t, f32);
  __syncthreads();
  for (int s = 128; s > 0; s >>= 1){
    if (t < s){ reds[t] += reds[t+s]; redss[t] += redss[t+s]; }
    __syncthreads();
  }
  if (t == 0){
    float m = reds[0] / 512.f;
    float sd = sqrtf(redss[0] / 512.f - m*m + 1e-5f);
    msh[0] = m; msh[1] = 1.f / sd;
    means[bv] = m; stds[bv] = sd; rstds[bv] = 1.f / sd;
  }
  __syncthreads();
  float mean = msh[0], rstd = msh[1];
  xn[t] = (xn[t] - mean) * rstd;
  xn[t+256] = (xn[t+256] - mean) * rstd;
  __syncthreads();
  {
    int p = t >> 2, q = t & 3;
    float tv[16];
    #pragma unroll
    for (int l = 0; l < 16; ++l){
      int xi = p*8 + l; if (xi > 511) xi = 511;   // edge pad
      tv[l] = xn[xi];
    }
    for (int dd = 0; dd < 32; ++dd){
      int d = q*32 + dd;
      float acc = peg[p*128 + d];
      #pragma unroll
      for (int l = 0; l < 16; ++l) acc += tv[l] * WpL[l*128 + d];
      Xf[p*128 + d] = acc;
    }
  }
  __syncthreads();
  if (t < 128){
    int p = t >> 1, half = t & 1;
    float s[8] = {0,0,0,0,0,0,0,0};
    for (int d = half*64; d < half*64 + 64; ++d){
      float xv = Xf[p*128 + d];
      #pragma unroll
      for (int e = 0; e < 8; ++e) s[e] += xv * ldin(Wg, d*8 + e, f32);
    }
    #pragma unroll
    for (int e = 0; e < 8; ++e) lp[(p*2 + half)*8 + e] = s[e];
  }
  __syncthreads();
  if (t < 64){
    int p = t;
    float lg[8];
    #pragma unroll
    for (int e = 0; e < 8; ++e) lg[e] = lp[(p*2)*8 + e] + lp[(p*2+1)*8 + e];
    float m = lg[0];
    #pragma unroll
    for (int e = 1; e < 8; ++e) m = fmaxf(m, lg[e]);
    float pr[8]; float se = 0.f;
    #pragma unroll
    for (int e = 0; e < 8; ++e){ pr[e] = __expf(lg[e] - m); se += pr[e]; }
    float inv = 1.f / se;
    float lse = m + logf(se);
    #pragma unroll
    for (int e = 0; e < 8; ++e) pr[e] *= inv;
    float best = -1.f; int bi = 0;
    #pragma unroll
    for (int e = 0; e < 8; ++e) if (pr[e] > best){ best = pr[e]; bi = e; }
    float sec = -1.f; int si = 0;
    #pragma unroll
    for (int e = 0; e < 8; ++e) if (e != bi && pr[e] > sec){ sec = pr[e]; si = e; }
    #pragma unroll
    for (int e = 0; e < 8; ++e){
      float w = (e == bi) ? best : ((e == si) ? sec : 0.f);
      cwg[(bv*64 + p)*8 + e] = w;
      taux[p*9 + e] = pr[e];
    }
    taux[p*9 + 8] = lse * lse;
    lp[p] = (float)bi; lp[64 + p] = (float)si;   // reuse lp for mask info
  }
  __syncthreads();
  if (t < 17){
    float s = 0.f;
    if (t < 8){ for (int p = 0; p < 64; ++p) s += taux[p*9 + t]; }
    else if (t < 16){
      int e = t - 8;
      for (int p = 0; p < 64; ++p)
        s += ((int)lp[p] == e || (int)lp[64+p] == e) ? 1.f : 0.f;
    }
    else { for (int p = 0; p < 64; ++p) s += taux[p*9 + 8]; }
    atomicAdd(sums + t, s);
  }
  // Xf -> bf16 xfbf (coalesced b128)
  #pragma unroll
  for (int pass = 0; pass < 4; ++pass){
    int idx = pass*256 + t;         // 1024 groups of 8
    int base = idx*8;
    bf16x8 o;
    #pragma unroll
    for (int j = 0; j < 8; ++j) o[j] = (short)f2bf(Xf[base + j]);
    *(bf16x8*)(xfbf + bv*8192 + base) = o;
  }
}

// ========== K3: per-(bv,e) dense FFN, MFMA, atomic Y ==========
__global__ __launch_bounds__(256, 3) void k_moe(const unsigned short* __restrict__ xfbf,
                                                const unsigned short* __restrict__ W1T,
                                                const unsigned short* __restrict__ W2T,
                                                const void* __restrict__ b1g,
                                                const int* cnt,
                                                const float* __restrict__ cwg,
                                                float* __restrict__ Yg){
  __shared__ __align__(16) char lds[53504];
  short* Xs  = (short*)(lds);            // [64][136]
  short* Bu1 = (short*)(lds + 17408);    // [64][136] W1 chunk; Ag [64][72] overlays
  short* Bu2 = (short*)(lds + 34816);    // [128][72] W2 chunk
  float* cws = (float*)(lds + 53248);    // [64]
  short* Ag  = Bu1;

  int bv = blockIdx.x >> 3, e = blockIdx.x & 7;
  int t = threadIdx.x;
  int f32 = (cnt[0] >= 4);
  int wave = t >> 6, lane = t & 63;
  int quad = lane >> 4, li = lane & 15;
  int r0 = (wave & 1) * 32;
  int c1 = (wave >> 1) * 32;
  int c2 = (wave >> 1) * 64;

  #pragma unroll
  for (int pass = 0; pass < 4; ++pass){
    int idx = pass*256 + t;
    int row = idx >> 4, kg = idx & 15;
    *(bf16x8*)(Xs + row*136 + kg*8) =
      *(const bf16x8*)(xfbf + (bv*64 + row)*128 + kg*8);
  }
  if (t < 64) cws[t] = cwg[(bv*64 + t)*8 + e];
  __syncthreads();
  // per-lane gate weights for the 8 rows this lane touches
  float cwv[2][4];
  #pragma unroll
  for (int rt = 0; rt < 2; ++rt)
    #pragma unroll
    for (int r = 0; r < 4; ++r)
      cwv[rt][r] = cws[r0 + rt*16 + quad*4 + r];

  f32x4 Yacc[2][4];
  #pragma unroll
  for (int a = 0; a < 2; ++a)
    #pragma unroll
    for (int bb = 0; bb < 4; ++bb){ f32x4 z = {0.f,0.f,0.f,0.f}; Yacc[a][bb] = z; }

  for (int hc = 0; hc < 8; ++hc){
    __syncthreads();               // (a) prev G2 reads of Bu1/Bu2 done
    #pragma unroll
    for (int pass = 0; pass < 4; ++pass){
      int idx = pass*256 + t;
      int row = idx >> 4, kg = idx & 15;
      *(bf16x8*)(Bu1 + row*136 + kg*8) =
        *(const bf16x8*)(W1T + e*65536 + (hc*64 + row)*128 + kg*8);
    }
    #pragma unroll
    for (int pass = 0; pass < 4; ++pass){
      int idx = pass*256 + t;
      int row = idx >> 3, kg = idx & 7;
      *(bf16x8*)(Bu2 + row*72 + kg*8) =
        *(const bf16x8*)(W2T + e*65536 + row*512 + hc*64 + kg*8);
    }
    __syncthreads();               // (b)
    // GEMM1: 64 tok x 64 h, K=128
    f32x4 acc1[2][2];
    #pragma unroll
    for (int a = 0; a < 2; ++a)
      #pragma unroll
      for (int bb = 0; bb < 2; ++bb){ f32x4 z = {0.f,0.f,0.f,0.f}; acc1[a][bb] = z; }
    #pragma unroll
    for (int ks = 0; ks < 4; ++ks){
      int kk = ks*32 + quad*8;
      bf16x8 a0 = *(const bf16x8*)(Xs + (r0 + li)*136 + kk);
      bf16x8 a1 = *(const bf16x8*)(Xs + (r0 + 16 + li)*136 + kk);
      bf16x8 b0 = *(const bf16x8*)(Bu1 + (c1 + li)*136 + kk);
      bf16x8 b1f = *(const bf16x8*)(Bu1 + (c1 + 16 + li)*136 + kk);
      acc1[0][0] = mfma16(a0, b0,  acc1[0][0]);
      acc1[0][1] = mfma16(a0, b1f, acc1[0][1]);
      acc1[1][0] = mfma16(a1, b0,  acc1[1][0]);
      acc1[1][1] = mfma16(a1, b1f, acc1[1][1]);
    }
    float bias0 = ldin(b1g, e*512 + hc*64 + c1 + li, f32);
    float bias1 = ldin(b1g, e*512 + hc*64 + c1 + 16 + li, f32);
    __syncthreads();               // (c) all G1 reads of Bu1 done before Ag overlay write
    #pragma unroll
    for (int rt = 0; rt < 2; ++rt){
      #pragma unroll
      for (int ct = 0; ct < 2; ++ct){
        float bias = ct ? bias1 : bias0;
        int colL = c1 + ct*16 + li;
        #pragma unroll
        for (int r = 0; r < 4; ++r){
          int row = r0 + rt*16 + quad*4 + r;
          float g = gelu_fast(acc1[rt][ct][r] + bias);
          Ag[row*72 + colL] = (short)f2bf(g * cwv[rt][r]);
        }
      }
    }
    __syncthreads();               // (d)
    // GEMM2: 64 tok x 128 d, K=64
    #pragma unroll
    for (int ks = 0; ks < 2; ++ks){
      int kk = ks*32 + quad*8;
      bf16x8 a0 = *(const bf16x8*)(Ag + (r0 + li)*72 + kk);
      bf16x8 a1 = *(const bf16x8*)(Ag + (r0 + 16 + li)*72 + kk);
      bf16x8 bb[4];
      #pragma unroll
      for (int ct = 0; ct < 4; ++ct)
        bb[ct] = *(const bf16x8*)(Bu2 + (c2 + ct*16 + li)*72 + kk);
      #pragma unroll
      for (int ct = 0; ct < 4; ++ct){
        Yacc[0][ct] = mfma16(a0, bb[ct], Yacc[0][ct]);
        Yacc[1][ct] = mfma16(a1, bb[ct], Yacc[1][ct]);
      }
    }
  }
  #pragma unroll
  for (int ct = 0; ct < 4; ++ct){
    int col = c2 + ct*16 + li;
    #pragma unroll
    for (int rt = 0; rt < 2; ++rt)
      #pragma unroll
      for (int r = 0; r < 4; ++r){
        int row = r0 + rt*16 + quad*4 + r;
        atomicAdd(Yg + (bv*64 + row)*128 + col, Yacc[rt][ct][r]);
      }
  }
}

// ========== K4: Y + sum_e cw*b2 -> flat bf16 [bv][d*64+p] ==========
__global__ __launch_bounds__(256) void k_flat(const float* __restrict__ Yg,
                                              const float* __restrict__ cwg,
                                              const void* __restrict__ b2g,
                                              const int* cnt,
                                              unsigned short* __restrict__ flatb){
  __shared__ float Yl[64*130];
  __shared__ float b2f[1024];
  __shared__ float cwl[512];
  int bv = blockIdx.x;
  int t = threadIdx.x;
  int f32 = (cnt[0] >= 4);
  #pragma unroll
  for (int pass = 0; pass < 32; ++pass){
    int idx = pass*256 + t;
    int row = idx >> 7, col = idx & 127;
    Yl[row*130 + col] = Yg[(bv*64 + row)*128 + col];
  }
  #pragma unroll
  for (int j = 0; j < 4; ++j) b2f[j*256 + t] = ldin(b2g, j*256 + t, f32);
  #pragma unroll
  for (int j = 0; j < 2; ++j) cwl[j*256 + t] = cwg[bv*512 + j*256 + t];
  __syncthreads();
  int d = t >> 1, ph = (t & 1) * 32;
  float b2c[8];
  #pragma unroll
  for (int e = 0; e < 8; ++e) b2c[e] = b2f[e*128 + d];
  unsigned short ob[32];
  for (int j = 0; j < 32; ++j){
    int p = ph + j;
    float add = 0.f;
    #pragma unroll
    for (int e = 0; e < 8; ++e) add += cwl[p*8 + e] * b2c[e];
    ob[j] = f2bf(Yl[p*130 + d] + add);
  }
  #pragma unroll
  for (int m = 0; m < 4; ++m)
    *(bf16x8*)(flatb + bv*8192 + d*64 + ph + m*8) = *(bf16x8*)(ob + m*8);
}

// ========== K5: head GEMM (M=256, N=96, K=8192; K-split 16) ==========
__global__ __launch_bounds__(256) void k_head(const unsigned short* __restrict__ flatb,
                                              const unsigned short* __restrict__ WhT,
                                              float* dec_acc){
  int t = threadIdx.x;
  int mt = blockIdx.x & 15, kc = blockIdx.x >> 4;
  int wave = t >> 6, lane = t & 63, quad = lane >> 4, li = lane & 15;
  int kbase = kc*512 + wave*128;
  f32x4 acc[6];
  #pragma unroll
  for (int nt = 0; nt < 6; ++nt){ f32x4 z = {0.f,0.f,0.f,0.f}; acc[nt] = z; }
  #pragma unroll
  for (int ks = 0; ks < 4; ++ks){
    int k = kbase + ks*32 + quad*8;
    bf16x8 a = *(const bf16x8*)(flatb + (mt*16 + li)*8192 + k);
    #pragma unroll
    for (int nt = 0; nt < 6; ++nt){
      bf16x8 b = *(const bf16x8*)(WhT + (nt*16 + li)*8192 + k);
      acc[nt] = mfma16(a, b, acc[nt]);
    }
  }
  __shared__ float redsh[4][16][96];
  #pragma unroll
  for (int nt = 0; nt < 6; ++nt)
    #pragma unroll
    for (int r = 0; r < 4; ++r)
      redsh[wave][quad*4 + r][nt*16 + li] = acc[nt][r];
  __syncthreads();
  #pragma unroll
  for (int u = 0; u < 6; ++u){
    int o = t*6 + u;
    int row = o / 96, col = o % 96;
    float s = redsh[0][row][col] + redsh[1][row][col] + redsh[2][row][col] + redsh[3][row][col];
    atomicAdd(dec_acc + (mt*16 + row)*96 + col, s);
  }
}

// ========== K6: de-norm + output + aux ==========
__global__ __launch_bounds__(256) void k_final(const float* __restrict__ dec_acc,
                                               const void* __restrict__ bh,
                                               const int* cnt,
                                               const float* __restrict__ means,
                                               const float* __restrict__ stds,
                                               const float* __restrict__ sums,
                                               void* out){
  int o = blockIdx.x*256 + threadIdx.x;   // 0..24575
  int f32 = (cnt[0] >= 4);
  int b = o / 3072, rem = o % 3072, j = rem >> 5, v = rem & 31;
  int bv = b*32 + v;
  float val = (dec_acc[bv*96 + j] + ldin(bh, j, f32)) * stds[bv] + means[bv];
  stout(out, o, val, f32);
  if (o == 0){
    float bal = 0.f;
    for (int e = 0; e < 8; ++e) bal += (sums[e] / 16384.f) * (sums[8+e] / 16384.f);
    bal = 8.f * bal / 2.f;
    float aux = 0.01f * bal + 0.001f * (sums[16] / 16384.f);
    stout(out, 24576, aux, f32);
  }
}

extern "C" void kernel_launch(void* const* d_in, const int* in_sizes, int n_in,
                              void* d_out, int out_size, void* d_ws, size_t ws_size,
                              hipStream_t stream){
  const void* xe = d_in[0];
  const void* Wp = d_in[4];
  const void* Wg = d_in[5];
  const void* W1 = d_in[6];
  const void* b1 = d_in[7];
  const void* W2 = d_in[8];
  const void* b2 = d_in[9];
  const void* Wh = d_in[10];
  const void* bh = d_in[11];

  char* ws = (char*)d_ws;
  int*   cnt   = (int*)(ws + OFF_CNT);
  float* sums  = (float*)(ws + OFF_SUMS);
  float* means = (float*)(ws + OFF_MEANS);
  float* stds  = (float*)(ws + OFF_STDS);
  float* rstds = (float*)(ws + OFF_RSTDS);
  float* pe    = (float*)(ws + OFF_PE);
  float* dec   = (float*)(ws + OFF_DEC);
  unsigned short* W1T   = (unsigned short*)(ws + OFF_W1T);
  unsigned short* W2T   = (unsigned short*)(ws + OFF_W2T);
  unsigned short* WhT   = (unsigned short*)(ws + OFF_WHT);
  float* cw    = (float*)(ws + OFF_CW);
  unsigned short* xfbf  = (unsigned short*)(ws + OFF_XFBF);
  unsigned short* flatb = (unsigned short*)(ws + OFF_FLATB);
  float* Yg    = (float*)(ws + OFF_YG);

  hipMemsetAsync(ws, 0, 134400, stream);                    // cnt/sums/stats/PE/dec
  hipMemsetAsync(ws + OFF_YG, 0, 8388608, stream);          // Y accumulator
  k_detect<<<64, 256, 0, stream>>>((const unsigned short*)xe, cnt);
  k_prep_tr<<<1793, 256, 0, stream>>>(W1, W2, Wh, cnt, pe, W1T, W2T, WhT);
  k_embed<<<256, 256, 0, stream>>>(xe, Wp, Wg, cnt, pe, means, stds, rstds,
                                   xfbf, cw, sums);
  k_moe<<<2048, 256, 0, stream>>>(xfbf, W1T, W2T, b1, cnt, cw, Yg);
  k_flat<<<256, 256, 0, stream>>>(Yg, cw, b2, cnt, flatb);
  k_head<<<256, 256, 0, stream>>>(flatb, WhT, dec);
  k_final<<<96, 256, 0, stream>>>(dec, bh, cnt, means, stds, sums, d_out);
}